// Round 12
// baseline (585.812 us; speedup 1.0000x reference)
//
#include <hip/hip_runtime.h>
#include <cstdint>
#include <cstddef>

// GCN 2-layer forward for MI355X — CSR gather + register-tiled GEMM.
// bf16 gather tables (XW1/HW2) to halve random-gather traffic.
// N=100000, E=1600000, IN_F=128, H_F=64, OUT_F=32.

#define IN_F 128
#define H_F 64
#define OUT_F 32

// Fixed-point scale for degree accumulation (low 40 bits of packed u64).
#define DEG_SCALE 16777216.0f  // 2^24
#define DEG_MASK ((1ULL << 40) - 1)

// bf16 helpers (round-to-nearest-even-ish via magic rounding)
__device__ __forceinline__ unsigned short f2bf(float f) {
    unsigned u = __float_as_uint(f);
    unsigned r = u + 0x7FFFu + ((u >> 16) & 1u);
    return (unsigned short)(r >> 16);
}
__device__ __forceinline__ float bf2f(unsigned short b) {
    return __uint_as_float(((unsigned)b) << 16);
}

// ---------------- dtype detection for edge_index (int64 vs int32) ------------
__global__ void k_detect_idx64(const long long* __restrict__ idx, int n_nodes,
                               int* __restrict__ flag) {
    __shared__ int ok;
    if (threadIdx.x == 0) ok = 1;
    __syncthreads();
    long long v = idx[threadIdx.x];  // first 64 values
    if (v < 0 || v >= (long long)n_nodes) atomicAnd(&ok, 0);
    __syncthreads();
    if (threadIdx.x == 0) *flag = ok;
}

__device__ __forceinline__ void decode_edge(const long long* __restrict__ idx64, int E,
                                            int e, int flag, int& r, int& c) {
    if (flag) {
        r = (int)idx64[e];
        c = (int)idx64[E + e];
    } else {
        const int* p = (const int*)idx64;
        r = p[e];
        c = p[E + e];
    }
}

// ---------------- histogram + weighted degree: ONE u64 atomic per edge --------
__global__ void k_edge_prep(const long long* __restrict__ idx64, const float* __restrict__ ew,
                            const int* __restrict__ flag,
                            unsigned long long* __restrict__ deg_cnt, int E) {
    int e = blockIdx.x * 256 + threadIdx.x;
    if (e >= E) return;
    int r, c;
    decode_edge(idx64, E, e, *flag, r, c);
    unsigned long long w = (unsigned long long)(ew[e] * DEG_SCALE + 0.5f);
    atomicAdd(&deg_cnt[c], (1ULL << 40) | w);
}

// unpack: cnt[i] = count; dinv[i] = rsqrt(deg + 1)  (+1 = self-loop weight)
__global__ void k_unpack(const unsigned long long* __restrict__ deg_cnt,
                         int* __restrict__ cnt, float* __restrict__ dinv, int n) {
    int i = blockIdx.x * blockDim.x + threadIdx.x;
    if (i < n) {
        unsigned long long p = deg_cnt[i];
        cnt[i] = (int)(p >> 40);
        float deg = (float)(p & DEG_MASK) * (1.0f / DEG_SCALE);
        dinv[i] = rsqrtf(deg + 1.0f);
    }
}

// ---------------- exclusive scan over cnt[N] (3 kernels) ----------------------
__global__ void k_scan_partial(const int* __restrict__ cnt, int* __restrict__ partial, int n) {
    __shared__ int s[256];
    int i = blockIdx.x * 256 + threadIdx.x;
    s[threadIdx.x] = (i < n) ? cnt[i] : 0;
    __syncthreads();
    for (int st = 128; st > 0; st >>= 1) {
        if (threadIdx.x < st) s[threadIdx.x] += s[threadIdx.x + st];
        __syncthreads();
    }
    if (threadIdx.x == 0) partial[blockIdx.x] = s[0];
}

__global__ void k_scan_top(int* __restrict__ partial, int nparts) {  // exclusive, in place
    __shared__ int s[512];
    int t = threadIdx.x;
    int mine = (t < nparts) ? partial[t] : 0;
    s[t] = mine;
    __syncthreads();
    for (int st = 1; st < 512; st <<= 1) {
        int v = (t >= st) ? s[t - st] : 0;
        __syncthreads();
        s[t] += v;
        __syncthreads();
    }
    if (t < nparts) partial[t] = s[t] - mine;
}

__global__ void k_scan_final(const int* __restrict__ cnt, const int* __restrict__ partial,
                             int* __restrict__ off, int* __restrict__ cursor, int n) {
    __shared__ int s[256];
    int t = threadIdx.x;
    int i = blockIdx.x * 256 + t;
    int mine = (i < n) ? cnt[i] : 0;
    s[t] = mine;
    __syncthreads();
    for (int st = 1; st < 256; st <<= 1) {
        int v = (t >= st) ? s[t - st] : 0;
        __syncthreads();
        s[t] += v;
        __syncthreads();
    }
    if (i < n) {
        int ex = s[t] - mine + partial[blockIdx.x];
        off[i] = ex;
        cursor[i] = ex;
    }
}

// ---------------- CSR build: group edges by destination, packed 8B stores ----
__global__ void k_reorder(const long long* __restrict__ idx64, const float* __restrict__ ew,
                          const int* __restrict__ flag, const float* __restrict__ dinv,
                          int* __restrict__ cursor, int2* __restrict__ csr, int E) {
    int e = blockIdx.x * 256 + threadIdx.x;
    if (e >= E) return;
    int r, c;
    decode_edge(idx64, E, e, *flag, r, c);
    float v = dinv[r] * ew[e] * dinv[c];
    int pos = atomicAdd(&cursor[c], 1);
    csr[pos] = make_int2(r, __float_as_int(v));
}

// ---------------- register-tiled GEMM: Yb[N,F] = bf16( X[N,K] @ W[K,F] ) ------
// Block: 256 threads, 128-row x F-col tile. X k-chunk staged transposed in LDS;
// W fully in LDS. Thread computes RPT rows x 4 cols in registers; stores bf16.
template <int K, int F>
__global__ __launch_bounds__(256) void k_gemm(const float* __restrict__ X,
                                              const float* __restrict__ W,
                                              unsigned short* __restrict__ Yb, int N) {
    constexpr int KC = 32;             // k-chunk
    constexpr int TC = F / 4;          // col groups (16 or 8)
    constexpr int TR = 256 / TC;       // row groups (16 or 32)
    constexpr int RPT = 128 / TR;      // rows per thread (8 or 4)
    constexpr int XP = 132;            // padded row length (16B aligned, bank-spread)
    __shared__ float Xs[KC][XP];
    __shared__ float Ws[K * F];

    for (int t = threadIdx.x; t < (K * F) / 4; t += 256)
        reinterpret_cast<float4*>(Ws)[t] = reinterpret_cast<const float4*>(W)[t];

    const int tc = threadIdx.x % TC;
    const int tr = threadIdx.x / TC;
    const int row0 = blockIdx.x * 128;

    float acc[RPT][4];
#pragma unroll
    for (int i = 0; i < RPT; ++i)
#pragma unroll
        for (int j = 0; j < 4; ++j) acc[i][j] = 0.f;

    for (int kc = 0; kc < K; kc += KC) {
        __syncthreads();
        // stage X[row0..row0+127][kc..kc+KC) transposed -> Xs[k][row]
#pragma unroll
        for (int t = threadIdx.x; t < 128 * (KC / 4); t += 256) {
            int r = t / (KC / 4);
            int k4 = t % (KC / 4);
            int n = row0 + r;
            float4 v = (n < N) ? *reinterpret_cast<const float4*>(X + (size_t)n * K + kc + k4 * 4)
                               : make_float4(0.f, 0.f, 0.f, 0.f);
            Xs[k4 * 4 + 0][r] = v.x;
            Xs[k4 * 4 + 1][r] = v.y;
            Xs[k4 * 4 + 2][r] = v.z;
            Xs[k4 * 4 + 3][r] = v.w;
        }
        __syncthreads();
#pragma unroll
        for (int k = 0; k < KC; ++k) {
            float4 w = *reinterpret_cast<const float4*>(&Ws[(kc + k) * F + tc * 4]);
            float xr[RPT];
#pragma unroll
            for (int i = 0; i < RPT / 4; ++i) {
                float4 xv = *reinterpret_cast<const float4*>(&Xs[k][tr * RPT + i * 4]);
                xr[i * 4 + 0] = xv.x;
                xr[i * 4 + 1] = xv.y;
                xr[i * 4 + 2] = xv.z;
                xr[i * 4 + 3] = xv.w;
            }
#pragma unroll
            for (int i = 0; i < RPT; ++i) {
                acc[i][0] += xr[i] * w.x;
                acc[i][1] += xr[i] * w.y;
                acc[i][2] += xr[i] * w.z;
                acc[i][3] += xr[i] * w.w;
            }
        }
    }
    // store: 4 bf16 (8B) per row
#pragma unroll
    for (int i = 0; i < RPT; ++i) {
        int n = row0 + tr * RPT + i;
        if (n < N) {
            ushort4 s;
            s.x = f2bf(acc[i][0]);
            s.y = f2bf(acc[i][1]);
            s.z = f2bf(acc[i][2]);
            s.w = f2bf(acc[i][3]);
            *reinterpret_cast<ushort4*>(Yb + (size_t)n * F + tc * 4) = s;
        }
    }
}

// ---------------- gather aggregation: one F-lane group per node --------------
// Out[n] = (RELU?) ( dinv[n]^2 * Yb[n] + sum_j val_j * Yb[row_j] + bias )
// Yb is bf16 (halves random-gather traffic); Out is f32. Unroll-4 for MLP.
template <int F, bool RELU>
__global__ void k_agg(const unsigned short* __restrict__ Yb, const int* __restrict__ off,
                      const int* __restrict__ cnt, const int2* __restrict__ csr,
                      const float* __restrict__ dinv, const float* __restrict__ bias,
                      float* __restrict__ Out, int N) {
    const int lane = threadIdx.x % F;
    const int sub = threadIdx.x / F;
    const int n = blockIdx.x * (256 / F) + sub;
    if (n >= N) return;
    float d = dinv[n];
    float acc = d * d * bf2f(Yb[(size_t)n * F + lane]);
    int j = off[n];
    const int e = j + cnt[n];
    for (; j + 3 < e; j += 4) {
        int2 c0 = csr[j], c1 = csr[j + 1], c2 = csr[j + 2], c3 = csr[j + 3];
        float y0 = bf2f(Yb[(size_t)c0.x * F + lane]);
        float y1 = bf2f(Yb[(size_t)c1.x * F + lane]);
        float y2 = bf2f(Yb[(size_t)c2.x * F + lane]);
        float y3 = bf2f(Yb[(size_t)c3.x * F + lane]);
        acc += __int_as_float(c0.y) * y0;
        acc += __int_as_float(c1.y) * y1;
        acc += __int_as_float(c2.y) * y2;
        acc += __int_as_float(c3.y) * y3;
    }
    for (; j < e; ++j) {
        int2 c0 = csr[j];
        acc += __int_as_float(c0.y) * bf2f(Yb[(size_t)c0.x * F + lane]);
    }
    acc += bias[lane];
    if (RELU) acc = acc > 0.f ? acc : 0.f;
    Out[(size_t)n * F + lane] = acc;
}

extern "C" void kernel_launch(void* const* d_in, const int* in_sizes, int n_in,
                              void* d_out, int out_size, void* d_ws, size_t ws_size,
                              hipStream_t stream) {
    const float* x = (const float*)d_in[0];
    const long long* idx = (const long long*)d_in[1];
    const float* ew = (const float*)d_in[2];
    const float* W1 = (const float*)d_in[3];
    const float* b1 = (const float*)d_in[4];
    const float* W2 = (const float*)d_in[5];
    const float* b2 = (const float*)d_in[6];
    float* out = (float*)d_out;

    const int N = in_sizes[0] / IN_F;   // 100000
    const int E = in_sizes[2];          // 1600000
    const int nparts = (N + 255) / 256; // 391 (<= 512 required by k_scan_top)

    // workspace carve-up (256B aligned)
    char* ws = (char*)d_ws;
    size_t off_b = 0;
    auto alloc = [&](size_t bytes) {
        void* p = ws + off_b;
        off_b += (bytes + 255) & ~(size_t)255;
        return p;
    };
    unsigned long long* deg_cnt = (unsigned long long*)alloc((size_t)N * 8);
    int* cnt = (int*)alloc((size_t)N * 4);
    float* dinv = (float*)alloc((size_t)N * 4);
    int* offs = (int*)alloc((size_t)N * 4);
    int* cursor = (int*)alloc((size_t)N * 4);
    int* partial = (int*)alloc((size_t)nparts * 4);
    int* flag = (int*)alloc(256);
    int2* csr = (int2*)alloc((size_t)E * 8);
    unsigned short* XW1 = (unsigned short*)alloc((size_t)N * H_F * 2);   // bf16
    float* H = (float*)alloc((size_t)N * H_F * 4);                       // f32 (gemm2 in)
    unsigned short* HW2 = (unsigned short*)alloc((size_t)N * OUT_F * 2); // bf16

    // ---- CSR + norm prep ----
    k_detect_idx64<<<1, 64, 0, stream>>>(idx, N, flag);
    hipMemsetAsync(deg_cnt, 0, (size_t)N * 8, stream);
    k_edge_prep<<<(E + 255) / 256, 256, 0, stream>>>(idx, ew, flag, deg_cnt, E);
    k_unpack<<<(N + 255) / 256, 256, 0, stream>>>(deg_cnt, cnt, dinv, N);
    k_scan_partial<<<nparts, 256, 0, stream>>>(cnt, partial, N);
    k_scan_top<<<1, 512, 0, stream>>>(partial, nparts);
    k_scan_final<<<nparts, 256, 0, stream>>>(cnt, partial, offs, cursor, N);
    k_reorder<<<(E + 255) / 256, 256, 0, stream>>>(idx, ew, flag, dinv, cursor, csr, E);

    // ---- layer 1: H = relu(D^-1/2 A D^-1/2 (x@W1) + b1) ----
    k_gemm<IN_F, H_F><<<(N + 127) / 128, 256, 0, stream>>>(x, W1, XW1, N);
    k_agg<H_F, true><<<(N + 3) / 4, 256, 0, stream>>>(XW1, offs, cnt, csr, dinv, b1, H, N);

    // ---- layer 2: out = D^-1/2 A D^-1/2 (H@W2) + b2 ----
    k_gemm<H_F, OUT_F><<<(N + 127) / 128, 256, 0, stream>>>(H, W2, HW2, N);
    k_agg<OUT_F, false><<<(N + 7) / 8, 256, 0, stream>>>(HW2, offs, cnt, csr, dinv, b2, out, N);
}

// Round 13
// 485.004 us; speedup vs baseline: 1.2079x; 1.2079x over previous
//
#include <hip/hip_runtime.h>
#include <cstdint>
#include <cstddef>

// GCN 2-layer forward for MI355X — CSR gather + register-tiled GEMM (f32 out)
// + separate f32->bf16 conversion for the gather tables.
// N=100000, E=1600000, IN_F=128, H_F=64, OUT_F=32.

#define IN_F 128
#define H_F 64
#define OUT_F 32

// Fixed-point scale for degree accumulation (low 40 bits of packed u64).
#define DEG_SCALE 16777216.0f  // 2^24
#define DEG_MASK ((1ULL << 40) - 1)

// bf16 helpers (round-to-nearest-even via magic rounding)
__device__ __forceinline__ unsigned short f2bf(float f) {
    unsigned u = __float_as_uint(f);
    unsigned r = u + 0x7FFFu + ((u >> 16) & 1u);
    return (unsigned short)(r >> 16);
}
__device__ __forceinline__ float bf2f(unsigned short b) {
    return __uint_as_float(((unsigned)b) << 16);
}

// ---------------- dtype detection for edge_index (int64 vs int32) ------------
__global__ void k_detect_idx64(const long long* __restrict__ idx, int n_nodes,
                               int* __restrict__ flag) {
    __shared__ int ok;
    if (threadIdx.x == 0) ok = 1;
    __syncthreads();
    long long v = idx[threadIdx.x];  // first 64 values
    if (v < 0 || v >= (long long)n_nodes) atomicAnd(&ok, 0);
    __syncthreads();
    if (threadIdx.x == 0) *flag = ok;
}

__device__ __forceinline__ void decode_edge(const long long* __restrict__ idx64, int E,
                                            int e, int flag, int& r, int& c) {
    if (flag) {
        r = (int)idx64[e];
        c = (int)idx64[E + e];
    } else {
        const int* p = (const int*)idx64;
        r = p[e];
        c = p[E + e];
    }
}

// ---------------- histogram + weighted degree: ONE u64 atomic per edge --------
__global__ void k_edge_prep(const long long* __restrict__ idx64, const float* __restrict__ ew,
                            const int* __restrict__ flag,
                            unsigned long long* __restrict__ deg_cnt, int E) {
    int e = blockIdx.x * 256 + threadIdx.x;
    if (e >= E) return;
    int r, c;
    decode_edge(idx64, E, e, *flag, r, c);
    unsigned long long w = (unsigned long long)(ew[e] * DEG_SCALE + 0.5f);
    atomicAdd(&deg_cnt[c], (1ULL << 40) | w);
}

// unpack: cnt[i] = count; dinv[i] = rsqrt(deg + 1)  (+1 = self-loop weight)
__global__ void k_unpack(const unsigned long long* __restrict__ deg_cnt,
                         int* __restrict__ cnt, float* __restrict__ dinv, int n) {
    int i = blockIdx.x * blockDim.x + threadIdx.x;
    if (i < n) {
        unsigned long long p = deg_cnt[i];
        cnt[i] = (int)(p >> 40);
        float deg = (float)(p & DEG_MASK) * (1.0f / DEG_SCALE);
        dinv[i] = rsqrtf(deg + 1.0f);
    }
}

// ---------------- exclusive scan over cnt[N] (3 kernels) ----------------------
__global__ void k_scan_partial(const int* __restrict__ cnt, int* __restrict__ partial, int n) {
    __shared__ int s[256];
    int i = blockIdx.x * 256 + threadIdx.x;
    s[threadIdx.x] = (i < n) ? cnt[i] : 0;
    __syncthreads();
    for (int st = 128; st > 0; st >>= 1) {
        if (threadIdx.x < st) s[threadIdx.x] += s[threadIdx.x + st];
        __syncthreads();
    }
    if (threadIdx.x == 0) partial[blockIdx.x] = s[0];
}

__global__ void k_scan_top(int* __restrict__ partial, int nparts) {  // exclusive, in place
    __shared__ int s[512];
    int t = threadIdx.x;
    int mine = (t < nparts) ? partial[t] : 0;
    s[t] = mine;
    __syncthreads();
    for (int st = 1; st < 512; st <<= 1) {
        int v = (t >= st) ? s[t - st] : 0;
        __syncthreads();
        s[t] += v;
        __syncthreads();
    }
    if (t < nparts) partial[t] = s[t] - mine;
}

__global__ void k_scan_final(const int* __restrict__ cnt, const int* __restrict__ partial,
                             int* __restrict__ off, int* __restrict__ cursor, int n) {
    __shared__ int s[256];
    int t = threadIdx.x;
    int i = blockIdx.x * 256 + t;
    int mine = (i < n) ? cnt[i] : 0;
    s[t] = mine;
    __syncthreads();
    for (int st = 1; st < 256; st <<= 1) {
        int v = (t >= st) ? s[t - st] : 0;
        __syncthreads();
        s[t] += v;
        __syncthreads();
    }
    if (i < n) {
        int ex = s[t] - mine + partial[blockIdx.x];
        off[i] = ex;
        cursor[i] = ex;
    }
}

// ---------------- CSR build: group edges by destination, packed 8B stores ----
__global__ void k_reorder(const long long* __restrict__ idx64, const float* __restrict__ ew,
                          const int* __restrict__ flag, const float* __restrict__ dinv,
                          int* __restrict__ cursor, int2* __restrict__ csr, int E) {
    int e = blockIdx.x * 256 + threadIdx.x;
    if (e >= E) return;
    int r, c;
    decode_edge(idx64, E, e, *flag, r, c);
    float v = dinv[r] * ew[e] * dinv[c];
    int pos = atomicAdd(&cursor[c], 1);
    csr[pos] = make_int2(r, __float_as_int(v));
}

// ---------------- register-tiled GEMM: Y[N,F] = X[N,K] @ W[K,F] (f32 out) ----
// Known-good codegen (round 11). Block: 256 threads, 128-row x F-col tile.
template <int K, int F>
__global__ __launch_bounds__(256) void k_gemm(const float* __restrict__ X,
                                              const float* __restrict__ W,
                                              float* __restrict__ Y, int N) {
    constexpr int KC = 32;             // k-chunk
    constexpr int TC = F / 4;          // col groups (16 or 8)
    constexpr int TR = 256 / TC;       // row groups (16 or 32)
    constexpr int RPT = 128 / TR;      // rows per thread (8 or 4)
    constexpr int XP = 132;            // padded row length (16B aligned, bank-spread)
    __shared__ float Xs[KC][XP];
    __shared__ float Ws[K * F];

    for (int t = threadIdx.x; t < (K * F) / 4; t += 256)
        reinterpret_cast<float4*>(Ws)[t] = reinterpret_cast<const float4*>(W)[t];

    const int tc = threadIdx.x % TC;
    const int tr = threadIdx.x / TC;
    const int row0 = blockIdx.x * 128;

    float acc[RPT][4];
#pragma unroll
    for (int i = 0; i < RPT; ++i)
#pragma unroll
        for (int j = 0; j < 4; ++j) acc[i][j] = 0.f;

    for (int kc = 0; kc < K; kc += KC) {
        __syncthreads();
        // stage X[row0..row0+127][kc..kc+KC) transposed -> Xs[k][row]
#pragma unroll
        for (int t = threadIdx.x; t < 128 * (KC / 4); t += 256) {
            int r = t / (KC / 4);
            int k4 = t % (KC / 4);
            int n = row0 + r;
            float4 v = (n < N) ? *reinterpret_cast<const float4*>(X + (size_t)n * K + kc + k4 * 4)
                               : make_float4(0.f, 0.f, 0.f, 0.f);
            Xs[k4 * 4 + 0][r] = v.x;
            Xs[k4 * 4 + 1][r] = v.y;
            Xs[k4 * 4 + 2][r] = v.z;
            Xs[k4 * 4 + 3][r] = v.w;
        }
        __syncthreads();
#pragma unroll
        for (int k = 0; k < KC; ++k) {
            float4 w = *reinterpret_cast<const float4*>(&Ws[(kc + k) * F + tc * 4]);
            float xr[RPT];
#pragma unroll
            for (int i = 0; i < RPT / 4; ++i) {
                float4 xv = *reinterpret_cast<const float4*>(&Xs[k][tr * RPT + i * 4]);
                xr[i * 4 + 0] = xv.x;
                xr[i * 4 + 1] = xv.y;
                xr[i * 4 + 2] = xv.z;
                xr[i * 4 + 3] = xv.w;
            }
#pragma unroll
            for (int i = 0; i < RPT; ++i) {
                acc[i][0] += xr[i] * w.x;
                acc[i][1] += xr[i] * w.y;
                acc[i][2] += xr[i] * w.z;
                acc[i][3] += xr[i] * w.w;
            }
        }
    }
    // store: float4 per row
#pragma unroll
    for (int i = 0; i < RPT; ++i) {
        int n = row0 + tr * RPT + i;
        if (n < N) {
            float4 v = make_float4(acc[i][0], acc[i][1], acc[i][2], acc[i][3]);
            *reinterpret_cast<float4*>(Y + (size_t)n * F + tc * 4) = v;
        }
    }
}

// ---------------- f32 -> bf16 streaming conversion (float4 -> ushort4) -------
__global__ void k_cvt_bf16(const float* __restrict__ Y, unsigned short* __restrict__ Yb,
                           int total4) {
    int i = blockIdx.x * 256 + threadIdx.x;
    if (i < total4) {
        float4 v = reinterpret_cast<const float4*>(Y)[i];
        ushort4 s;
        s.x = f2bf(v.x);
        s.y = f2bf(v.y);
        s.z = f2bf(v.z);
        s.w = f2bf(v.w);
        reinterpret_cast<ushort4*>(Yb)[i] = s;
    }
}

// ---------------- gather aggregation: one F-lane group per node --------------
// Out[n] = (RELU?) ( dinv[n]^2 * Yb[n] + sum_j val_j * Yb[row_j] + bias )
// Yb is bf16 (halves random-gather traffic); Out is f32. Unroll-4.
template <int F, bool RELU>
__global__ void k_agg(const unsigned short* __restrict__ Yb, const int* __restrict__ off,
                      const int* __restrict__ cnt, const int2* __restrict__ csr,
                      const float* __restrict__ dinv, const float* __restrict__ bias,
                      float* __restrict__ Out, int N) {
    const int lane = threadIdx.x % F;
    const int sub = threadIdx.x / F;
    const int n = blockIdx.x * (256 / F) + sub;
    if (n >= N) return;
    float d = dinv[n];
    float acc = d * d * bf2f(Yb[(size_t)n * F + lane]);
    int j = off[n];
    const int e = j + cnt[n];
    for (; j + 3 < e; j += 4) {
        int2 c0 = csr[j], c1 = csr[j + 1], c2 = csr[j + 2], c3 = csr[j + 3];
        float y0 = bf2f(Yb[(size_t)c0.x * F + lane]);
        float y1 = bf2f(Yb[(size_t)c1.x * F + lane]);
        float y2 = bf2f(Yb[(size_t)c2.x * F + lane]);
        float y3 = bf2f(Yb[(size_t)c3.x * F + lane]);
        acc += __int_as_float(c0.y) * y0;
        acc += __int_as_float(c1.y) * y1;
        acc += __int_as_float(c2.y) * y2;
        acc += __int_as_float(c3.y) * y3;
    }
    for (; j < e; ++j) {
        int2 c0 = csr[j];
        acc += __int_as_float(c0.y) * bf2f(Yb[(size_t)c0.x * F + lane]);
    }
    acc += bias[lane];
    if (RELU) acc = acc > 0.f ? acc : 0.f;
    Out[(size_t)n * F + lane] = acc;
}

extern "C" void kernel_launch(void* const* d_in, const int* in_sizes, int n_in,
                              void* d_out, int out_size, void* d_ws, size_t ws_size,
                              hipStream_t stream) {
    const float* x = (const float*)d_in[0];
    const long long* idx = (const long long*)d_in[1];
    const float* ew = (const float*)d_in[2];
    const float* W1 = (const float*)d_in[3];
    const float* b1 = (const float*)d_in[4];
    const float* W2 = (const float*)d_in[5];
    const float* b2 = (const float*)d_in[6];
    float* out = (float*)d_out;

    const int N = in_sizes[0] / IN_F;   // 100000
    const int E = in_sizes[2];          // 1600000
    const int nparts = (N + 255) / 256; // 391 (<= 512 required by k_scan_top)

    // workspace carve-up (256B aligned)
    char* ws = (char*)d_ws;
    size_t off_b = 0;
    auto alloc = [&](size_t bytes) {
        void* p = ws + off_b;
        off_b += (bytes + 255) & ~(size_t)255;
        return p;
    };
    unsigned long long* deg_cnt = (unsigned long long*)alloc((size_t)N * 8);
    int* cnt = (int*)alloc((size_t)N * 4);
    float* dinv = (float*)alloc((size_t)N * 4);
    int* offs = (int*)alloc((size_t)N * 4);
    int* cursor = (int*)alloc((size_t)N * 4);
    int* partial = (int*)alloc((size_t)nparts * 4);
    int* flag = (int*)alloc(256);
    int2* csr = (int2*)alloc((size_t)E * 8);
    float* Yf = (float*)alloc((size_t)N * H_F * 4);                       // f32 gemm out (shared L1/L2)
    unsigned short* XW1b = (unsigned short*)alloc((size_t)N * H_F * 2);   // bf16 gather table L1
    float* H = (float*)alloc((size_t)N * H_F * 4);                        // f32 (gemm2 in)
    unsigned short* HW2b = (unsigned short*)alloc((size_t)N * OUT_F * 2); // bf16 gather table L2

    // ---- CSR + norm prep ----
    k_detect_idx64<<<1, 64, 0, stream>>>(idx, N, flag);
    hipMemsetAsync(deg_cnt, 0, (size_t)N * 8, stream);
    k_edge_prep<<<(E + 255) / 256, 256, 0, stream>>>(idx, ew, flag, deg_cnt, E);
    k_unpack<<<(N + 255) / 256, 256, 0, stream>>>(deg_cnt, cnt, dinv, N);
    k_scan_partial<<<nparts, 256, 0, stream>>>(cnt, partial, N);
    k_scan_top<<<1, 512, 0, stream>>>(partial, nparts);
    k_scan_final<<<nparts, 256, 0, stream>>>(cnt, partial, offs, cursor, N);
    k_reorder<<<(E + 255) / 256, 256, 0, stream>>>(idx, ew, flag, dinv, cursor, csr, E);

    // ---- layer 1: H = relu(D^-1/2 A D^-1/2 (x@W1) + b1) ----
    k_gemm<IN_F, H_F><<<(N + 127) / 128, 256, 0, stream>>>(x, W1, Yf, N);
    {
        int total4 = (N * H_F) / 4;
        k_cvt_bf16<<<(total4 + 255) / 256, 256, 0, stream>>>(Yf, XW1b, total4);
    }
    k_agg<H_F, true><<<(N + 3) / 4, 256, 0, stream>>>(XW1b, offs, cnt, csr, dinv, b1, H, N);

    // ---- layer 2: out = D^-1/2 A D^-1/2 (H@W2) + b2 ----
    k_gemm<H_F, OUT_F><<<(N + 127) / 128, 256, 0, stream>>>(H, W2, Yf, N);
    {
        int total4 = (N * OUT_F) / 4;
        k_cvt_bf16<<<(total4 + 255) / 256, 256, 0, stream>>>(Yf, HW2b, total4);
    }
    k_agg<OUT_F, false><<<(N + 7) / 8, 256, 0, stream>>>(HW2b, offs, cnt, csr, dinv, b2, out, N);
}